// Round 2
// baseline (977.134 us; speedup 1.0000x reference)
//
#include <hip/hip_runtime.h>
#include <cstddef>

// Problem constants (from reference): N=Q=16384, D=3.
// d_out layout (flat float32, outputs concatenated in return order):
//   [0, Q*N)              mask  (0.0 / 1.0)
//   [Q*N, Q*N + Q + 1)    row_splits (exclusive-scan of counts, as float)
//   [Q*N + Q + 1, end)    weights (sqdist where mask else 0)

namespace {

constexpr int NPTS = 16384;
constexpr int NQ   = 16384;
constexpr int QB   = 8;     // queries per block
constexpr int TPB  = 256;   // threads per block
constexpr int VEC  = 4;     // points per thread per iteration (wave-strided)
constexpr int ITERS = NPTS / (TPB * VEC); // 16

__device__ __forceinline__ float mulrn(float a, float b) { return __fmul_rn(a, b); }
__device__ __forceinline__ float addrn(float a, float b) { return __fadd_rn(a, b); }

__global__ __launch_bounds__(TPB) void ball_kernel(
    const float* __restrict__ data,      // [N,3]
    const float* __restrict__ queries,   // [Q,3]
    const float* __restrict__ radius_p,  // [1]
    float* __restrict__ out,
    int* __restrict__ counts)            // [Q] in workspace
{
    const int tid = threadIdx.x;
    const int q0  = blockIdx.x * QB;

    __shared__ float qs[QB * 3];
    __shared__ int   scnt[QB];
    if (tid < QB * 3) qs[tid] = queries[(size_t)q0 * 3 + tid];
    if (tid < QB)     scnt[tid] = 0;
    __syncthreads();

    const float r  = radius_p[0];
    const float r2 = mulrn(r, r);

    float qx[QB], qy[QB], qz[QB], q2v[QB];
#pragma unroll
    for (int i = 0; i < QB; ++i) {
        qx[i] = qs[3 * i + 0];
        qy[i] = qs[3 * i + 1];
        qz[i] = qs[3 * i + 2];
        q2v[i] = addrn(addrn(mulrn(qx[i], qx[i]), mulrn(qy[i], qy[i])),
                       mulrn(qz[i], qz[i]));
    }

    int cnt[QB];
#pragma unroll
    for (int i = 0; i < QB; ++i) cnt[i] = 0;

    float* __restrict__ mask = out;
    float* __restrict__ wts  = out + ((size_t)NQ * NPTS + NQ + 1);

    for (int it = 0; it < ITERS; ++it) {
        const int pbase = it * (TPB * VEC) + tid; // wave-strided: p_j = pbase + j*TPB

        float dx[VEC], dy[VEC], dz[VEC], d2[VEC];
#pragma unroll
        for (int j = 0; j < VEC; ++j) {
            const int p = pbase + j * TPB;
            const float* dp = data + (size_t)p * 3;
            // 12B per lane, lanes contiguous -> dwordx3, fully coalesced
            dx[j] = dp[0];
            dy[j] = dp[1];
            dz[j] = dp[2];
            d2[j] = addrn(addrn(mulrn(dx[j], dx[j]), mulrn(dy[j], dy[j])),
                          mulrn(dz[j], dz[j]));
        }

#pragma unroll
        for (int q = 0; q < QB; ++q) {
            float* __restrict__ mrow = mask + (size_t)(q0 + q) * NPTS + pbase;
            float* __restrict__ wrow = wts  + (size_t)(q0 + q) * NPTS + pbase;
#pragma unroll
            for (int j = 0; j < VEC; ++j) {
                const float dot = addrn(addrn(mulrn(qx[q], dx[j]), mulrn(qy[q], dy[j])),
                                        mulrn(qz[q], dz[j]));
                float sq = __fsub_rn(addrn(q2v[q], d2[j]), mulrn(2.0f, dot));
                sq = fmaxf(sq, 0.0f);
                const bool in = (sq <= r2);
                // lanes write 64 consecutive dwords -> 256B coalesced; NT keeps L2
                // free for the data array the whole grid re-reads.
                __builtin_nontemporal_store(in ? 1.0f : 0.0f, mrow + j * TPB);
                __builtin_nontemporal_store(in ? sq : 0.0f,   wrow + j * TPB);
                cnt[q] += in ? 1 : 0;
            }
        }
    }

    // Block reduction of per-thread counts (wave shfl, then LDS atomics).
#pragma unroll
    for (int q = 0; q < QB; ++q) {
        int v = cnt[q];
        for (int off = 32; off >= 1; off >>= 1) v += __shfl_down(v, off);
        if ((tid & 63) == 0) atomicAdd(&scnt[q], v);
    }
    __syncthreads();
    if (tid < QB) counts[q0 + tid] = scnt[tid];
}

constexpr int STPB  = 256;
constexpr int CHUNK = NQ / STPB; // 64

__global__ __launch_bounds__(STPB) void scan_kernel(
    const int* __restrict__ counts, float* __restrict__ out)
{
    __shared__ int sums[STPB];
    const int tid  = threadIdx.x;
    const int base = tid * CHUNK;

    int s = 0;
    for (int i = 0; i < CHUNK; ++i) s += counts[base + i];
    sums[tid] = s;
    __syncthreads();

    // Hillis-Steele inclusive scan over 256 partial sums
    for (int off = 1; off < STPB; off <<= 1) {
        int v = 0;
        if (tid >= off) v = sums[tid - off];
        __syncthreads();
        sums[tid] += v;
        __syncthreads();
    }

    int run = (tid == 0) ? 0 : sums[tid - 1];
    float* rs = out + (size_t)NQ * NPTS;
    if (tid == 0) rs[0] = 0.0f;
    for (int i = 0; i < CHUNK; ++i) {
        run += counts[base + i];
        rs[base + i + 1] = (float)run;
    }
}

} // namespace

extern "C" void kernel_launch(void* const* d_in, const int* in_sizes, int n_in,
                              void* d_out, int out_size, void* d_ws, size_t ws_size,
                              hipStream_t stream) {
    const float* data    = (const float*)d_in[0];
    const float* queries = (const float*)d_in[1];
    const float* radius  = (const float*)d_in[2];
    float* out  = (float*)d_out;
    int* counts = (int*)d_ws;

    hipLaunchKernelGGL(ball_kernel, dim3(NQ / QB), dim3(TPB), 0, stream,
                       data, queries, radius, out, counts);
    hipLaunchKernelGGL(scan_kernel, dim3(1), dim3(STPB), 0, stream, counts, out);
}

// Round 3
// 811.958 us; speedup vs baseline: 1.2034x; 1.2034x over previous
//
#include <hip/hip_runtime.h>
#include <cstddef>

// Problem constants (from reference): N=Q=16384, D=3.
// d_out layout (flat float32, outputs concatenated in return order):
//   [0, Q*N)              mask  (0.0 / 1.0)
//   [Q*N, Q*N + Q + 1)    row_splits (exclusive-scan of counts, as float)
//   [Q*N + Q + 1, end)    weights (sqdist where mask else 0)

namespace {

constexpr int NPTS = 16384;
constexpr int NQ   = 16384;
constexpr int QB   = 8;     // queries per block
constexpr int TPB  = 256;   // threads per block
constexpr int VEC  = 4;     // points per thread per iteration (wave-strided)
constexpr int ITERS = NPTS / (TPB * VEC); // 16

__device__ __forceinline__ float mulrn(float a, float b) { return __fmul_rn(a, b); }
__device__ __forceinline__ float addrn(float a, float b) { return __fadd_rn(a, b); }

__global__ __launch_bounds__(TPB) void ball_kernel(
    const float* __restrict__ data,      // [N,3]
    const float* __restrict__ queries,   // [Q,3]
    const float* __restrict__ radius_p,  // [1]
    float* __restrict__ out,
    int* __restrict__ counts)            // [Q] in workspace
{
    const int tid = threadIdx.x;
    const int q0  = blockIdx.x * QB;

    __shared__ float qs[QB * 3];
    __shared__ int   scnt[QB];
    if (tid < QB * 3) qs[tid] = queries[(size_t)q0 * 3 + tid];
    if (tid < QB)     scnt[tid] = 0;
    __syncthreads();

    const float r  = radius_p[0];
    const float r2 = mulrn(r, r);

    float qx[QB], qy[QB], qz[QB], q2v[QB];
#pragma unroll
    for (int i = 0; i < QB; ++i) {
        qx[i] = qs[3 * i + 0];
        qy[i] = qs[3 * i + 1];
        qz[i] = qs[3 * i + 2];
        q2v[i] = addrn(addrn(mulrn(qx[i], qx[i]), mulrn(qy[i], qy[i])),
                       mulrn(qz[i], qz[i]));
    }

    int cnt[QB];
#pragma unroll
    for (int i = 0; i < QB; ++i) cnt[i] = 0;

    float* __restrict__ mask = out;
    float* __restrict__ wts  = out + ((size_t)NQ * NPTS + NQ + 1);

    for (int it = 0; it < ITERS; ++it) {
        const int pbase = it * (TPB * VEC) + tid; // wave-strided: p_j = pbase + j*TPB

        float dx[VEC], dy[VEC], dz[VEC], d2[VEC];
#pragma unroll
        for (int j = 0; j < VEC; ++j) {
            const int p = pbase + j * TPB;
            const float* dp = data + (size_t)p * 3;
            // 12B per lane, lanes contiguous -> dwordx3, fully coalesced
            dx[j] = dp[0];
            dy[j] = dp[1];
            dz[j] = dp[2];
            d2[j] = addrn(addrn(mulrn(dx[j], dx[j]), mulrn(dy[j], dy[j])),
                          mulrn(dz[j], dz[j]));
        }

#pragma unroll
        for (int q = 0; q < QB; ++q) {
            float* __restrict__ mrow = mask + (size_t)(q0 + q) * NPTS + pbase;
            float* __restrict__ wrow = wts  + (size_t)(q0 + q) * NPTS + pbase;
#pragma unroll
            for (int j = 0; j < VEC; ++j) {
                const float dot = addrn(addrn(mulrn(qx[q], dx[j]), mulrn(qy[q], dy[j])),
                                        mulrn(qz[q], dz[j]));
                float sq = __fsub_rn(addrn(q2v[q], d2[j]), mulrn(2.0f, dot));
                sq = fmaxf(sq, 0.0f);
                const bool in = (sq <= r2);
                // lanes write 64 consecutive dwords -> 256B fully-coalesced,
                // full 64B lines at L2. Plain stores (NT regressed: R2 post-mortem).
                mrow[j * TPB] = in ? 1.0f : 0.0f;
                wrow[j * TPB] = in ? sq : 0.0f;
                cnt[q] += in ? 1 : 0;
            }
        }
    }

    // Block reduction of per-thread counts (wave shfl, then LDS atomics).
#pragma unroll
    for (int q = 0; q < QB; ++q) {
        int v = cnt[q];
        for (int off = 32; off >= 1; off >>= 1) v += __shfl_down(v, off);
        if ((tid & 63) == 0) atomicAdd(&scnt[q], v);
    }
    __syncthreads();
    if (tid < QB) counts[q0 + tid] = scnt[tid];
}

constexpr int STPB  = 256;
constexpr int CHUNK = NQ / STPB; // 64

__global__ __launch_bounds__(STPB) void scan_kernel(
    const int* __restrict__ counts, float* __restrict__ out)
{
    __shared__ int sums[STPB];
    const int tid  = threadIdx.x;
    const int base = tid * CHUNK;

    int s = 0;
    for (int i = 0; i < CHUNK; ++i) s += counts[base + i];
    sums[tid] = s;
    __syncthreads();

    // Hillis-Steele inclusive scan over 256 partial sums
    for (int off = 1; off < STPB; off <<= 1) {
        int v = 0;
        if (tid >= off) v = sums[tid - off];
        __syncthreads();
        sums[tid] += v;
        __syncthreads();
    }

    int run = (tid == 0) ? 0 : sums[tid - 1];
    float* rs = out + (size_t)NQ * NPTS;
    if (tid == 0) rs[0] = 0.0f;
    for (int i = 0; i < CHUNK; ++i) {
        run += counts[base + i];
        rs[base + i + 1] = (float)run;
    }
}

} // namespace

extern "C" void kernel_launch(void* const* d_in, const int* in_sizes, int n_in,
                              void* d_out, int out_size, void* d_ws, size_t ws_size,
                              hipStream_t stream) {
    const float* data    = (const float*)d_in[0];
    const float* queries = (const float*)d_in[1];
    const float* radius  = (const float*)d_in[2];
    float* out  = (float*)d_out;
    int* counts = (int*)d_ws;

    hipLaunchKernelGGL(ball_kernel, dim3(NQ / QB), dim3(TPB), 0, stream,
                       data, queries, radius, out, counts);
    hipLaunchKernelGGL(scan_kernel, dim3(1), dim3(STPB), 0, stream, counts, out);
}

// Round 4
// 438.637 us; speedup vs baseline: 2.2277x; 1.8511x over previous
//
#include <hip/hip_runtime.h>
#include <cstddef>

// N=Q=16384, D=3. d_out (flat f32): mask [Q*N] | row_splits [Q+1] | weights [Q*N].
// Weights region starts at abs elem ≡ 1 (mod 4); aligned weights quads therefore
// cover row elems {4k-1..4k+2}. Slot 0 via shfl_up / recompute (see R4 notes).

namespace {

constexpr int NPTS = 16384;
constexpr int NQ   = 16384;
constexpr int QB   = 8;     // queries per block
constexpr int TPB  = 256;   // threads per block
constexpr int VEC  = 4;     // consecutive points per thread per iteration
constexpr int ITERS = NPTS / (TPB * VEC); // 16

__device__ __forceinline__ float mulrn(float a, float b) { return __fmul_rn(a, b); }
__device__ __forceinline__ float addrn(float a, float b) { return __fadd_rn(a, b); }

__global__ __launch_bounds__(TPB) void ball_kernel(
    const float* __restrict__ data,      // [N,3]
    const float* __restrict__ queries,   // [Q,3]
    const float* __restrict__ radius_p,  // [1]
    float* __restrict__ out,
    int* __restrict__ counts)            // [Q] in workspace
{
    const int tid  = threadIdx.x;
    const int lane = tid & 63;
    const int q0   = blockIdx.x * QB;

    __shared__ float qs[(QB + 1) * 3];   // queries q0-1 .. q0+QB-1
    __shared__ int   scnt[QB];
    if (tid < (QB + 1) * 3) {
        int src = q0 * 3 - 3 + tid;
        if (src < 0) src = 0;            // block 0 dummy; its row-head slot is
                                         // row_splits[Q], overwritten by scan.
        qs[tid] = queries[src];
    }
    if (tid < QB) scnt[tid] = 0;
    __syncthreads();

    const float r  = radius_p[0];
    const float r2 = mulrn(r, r);

    // Last data point (for row-head weights slots).
    const float lxx = data[(size_t)(NPTS - 1) * 3 + 0];
    const float lyy = data[(size_t)(NPTS - 1) * 3 + 1];
    const float lzz = data[(size_t)(NPTS - 1) * 3 + 2];
    const float l2  = addrn(addrn(mulrn(lxx, lxx), mulrn(lyy, lyy)), mulrn(lzz, lzz));

    float qx[QB], qy[QB], qz[QB], q2v[QB], whead[QB];
#pragma unroll
    for (int i = 0; i < QB; ++i) {
        qx[i] = qs[3 * (i + 1) + 0];
        qy[i] = qs[3 * (i + 1) + 1];
        qz[i] = qs[3 * (i + 1) + 2];
        q2v[i] = addrn(addrn(mulrn(qx[i], qx[i]), mulrn(qy[i], qy[i])),
                       mulrn(qz[i], qz[i]));
        // weight of (query q0+i-1, point NPTS-1) -> previous row's last element
        const float px = qs[3 * i + 0], py = qs[3 * i + 1], pz = qs[3 * i + 2];
        const float p2 = addrn(addrn(mulrn(px, px), mulrn(py, py)), mulrn(pz, pz));
        const float dt = addrn(addrn(mulrn(px, lxx), mulrn(py, lyy)), mulrn(pz, lzz));
        float sq = __fsub_rn(addrn(p2, l2), mulrn(2.0f, dt));
        sq = fmaxf(sq, 0.0f);
        whead[i] = (sq <= r2) ? sq : 0.0f;
    }

    int cnt[QB];
#pragma unroll
    for (int i = 0; i < QB; ++i) cnt[i] = 0;

    float* __restrict__ mask = out;
    float* __restrict__ wts  = out + ((size_t)NQ * NPTS + NQ + 1);

    for (int it = 0; it < ITERS; ++it) {
        const int nb = (it * TPB + tid) * VEC;
        const float4 dA = *reinterpret_cast<const float4*>(data + (size_t)nb * 3 + 0);
        const float4 dB = *reinterpret_cast<const float4*>(data + (size_t)nb * 3 + 4);
        const float4 dC = *reinterpret_cast<const float4*>(data + (size_t)nb * 3 + 8);
        const float dx[VEC] = {dA.x, dA.w, dB.z, dC.y};
        const float dy[VEC] = {dA.y, dB.x, dB.w, dC.z};
        const float dz[VEC] = {dA.z, dB.y, dC.x, dC.w};
        float d2[VEC];
#pragma unroll
        for (int j = 0; j < VEC; ++j)
            d2[j] = addrn(addrn(mulrn(dx[j], dx[j]), mulrn(dy[j], dy[j])),
                          mulrn(dz[j], dz[j]));

        // Left-neighbor point (nb-1), clamped at 0 (nb==0 slot comes from whead).
        const int pm1 = (nb == 0) ? 0 : nb - 1;
        const float mx = data[(size_t)pm1 * 3 + 0];
        const float my = data[(size_t)pm1 * 3 + 1];
        const float mz = data[(size_t)pm1 * 3 + 2];
        const float m2 = addrn(addrn(mulrn(mx, mx), mulrn(my, my)), mulrn(mz, mz));

        const bool rowhead = (tid == 0 && it == 0);

#pragma unroll
        for (int q = 0; q < QB; ++q) {
            float m[VEC], w[VEC];
#pragma unroll
            for (int j = 0; j < VEC; ++j) {
                const float dot = addrn(addrn(mulrn(qx[q], dx[j]), mulrn(qy[q], dy[j])),
                                        mulrn(qz[q], dz[j]));
                float sq = __fsub_rn(addrn(q2v[q], d2[j]), mulrn(2.0f, dot));
                sq = fmaxf(sq, 0.0f);
                const bool in = (sq <= r2);
                m[j] = in ? 1.0f : 0.0f;
                w[j] = in ? sq : 0.0f;
                cnt[q] += in ? 1 : 0;
            }
            // Slot 0 of the aligned weights quad = w(point nb-1):
            //   lanes>0: previous lane's w[3] via shfl; lane 0: recompute directly.
            const float dotm = addrn(addrn(mulrn(qx[q], mx), mulrn(qy[q], my)),
                                     mulrn(qz[q], mz));
            float sqm = __fsub_rn(addrn(q2v[q], m2), mulrn(2.0f, dotm));
            sqm = fmaxf(sqm, 0.0f);
            const float wprev = (sqm <= r2) ? sqm : 0.0f;
            const float wsh = __shfl_up(w[3], 1);
            float slot0 = (lane == 0) ? wprev : wsh;
            if (rowhead) slot0 = whead[q];

            const size_t row = (size_t)(q0 + q) * NPTS;
            *reinterpret_cast<float4*>(mask + row + nb) =
                make_float4(m[0], m[1], m[2], m[3]);
            *reinterpret_cast<float4*>(wts + row + nb - 1) =
                make_float4(slot0, w[0], w[1], w[2]);
        }
    }

    // Very last weights element (row NQ-1, elem NPTS-1) has no quad owner.
    if (q0 == NQ - QB && tid == TPB - 1) {
        const float dot = addrn(addrn(mulrn(qx[QB-1], lxx), mulrn(qy[QB-1], lyy)),
                                mulrn(qz[QB-1], lzz));
        float sq = __fsub_rn(addrn(q2v[QB-1], l2), mulrn(2.0f, dot));
        sq = fmaxf(sq, 0.0f);
        wts[(size_t)(NQ - 1) * NPTS + (NPTS - 1)] = (sq <= r2) ? sq : 0.0f;
    }

    // Block reduction of per-thread counts (wave shfl, then LDS atomics).
#pragma unroll
    for (int q = 0; q < QB; ++q) {
        int v = cnt[q];
        for (int off = 32; off >= 1; off >>= 1) v += __shfl_down(v, off);
        if ((tid & 63) == 0) atomicAdd(&scnt[q], v);
    }
    __syncthreads();
    if (tid < QB) counts[q0 + tid] = scnt[tid];
}

constexpr int STPB  = 256;
constexpr int CHUNK = NQ / STPB; // 64

__global__ __launch_bounds__(STPB) void scan_kernel(
    const int* __restrict__ counts, float* __restrict__ out)
{
    __shared__ int sums[STPB];
    const int tid  = threadIdx.x;
    const int base = tid * CHUNK;

    int s = 0;
    for (int i = 0; i < CHUNK; ++i) s += counts[base + i];
    sums[tid] = s;
    __syncthreads();

    for (int off = 1; off < STPB; off <<= 1) {
        int v = 0;
        if (tid >= off) v = sums[tid - off];
        __syncthreads();
        sums[tid] += v;
        __syncthreads();
    }

    int run = (tid == 0) ? 0 : sums[tid - 1];
    float* rs = out + (size_t)NQ * NPTS;
    if (tid == 0) rs[0] = 0.0f;
    for (int i = 0; i < CHUNK; ++i) {
        run += counts[base + i];
        rs[base + i + 1] = (float)run;
    }
}

} // namespace

extern "C" void kernel_launch(void* const* d_in, const int* in_sizes, int n_in,
                              void* d_out, int out_size, void* d_ws, size_t ws_size,
                              hipStream_t stream) {
    const float* data    = (const float*)d_in[0];
    const float* queries = (const float*)d_in[1];
    const float* radius  = (const float*)d_in[2];
    float* out  = (float*)d_out;
    int* counts = (int*)d_ws;

    hipLaunchKernelGGL(ball_kernel, dim3(NQ / QB), dim3(TPB), 0, stream,
                       data, queries, radius, out, counts);
    hipLaunchKernelGGL(scan_kernel, dim3(1), dim3(STPB), 0, stream, counts, out);
}